// Round 1
// baseline (198.664 us; speedup 1.0000x reference)
//
#include <hip/hip_runtime.h>
#include <hip/hip_cooperative_groups.h>
#include <stdint.h>

namespace cg = cooperative_groups;

// ---------------------------------------------------------------------------
// Speaker pairwise loss. R10 = R9's fused cooperative kernel, FIXED so it
// actually launches. R9's profile showed pair_kernel dispatches (ord 1015,
// 1249...) -> the occupancy check failed and the split fallback ran; 198.2us
// == R8's 199.6us. Root cause: mega_kernel had no min-waves bound, so the
// allocator was free to exceed 256 VGPRs -> 1 block/CU -> maxb*256=256 < 512.
// Fix: __launch_bounds__(256, 2) caps VGPR at 256/wave (2 waves/SIMD = 2
// blocks/CU = 512 co-resident blocks; LDS 34KB allows 4/CU). pair_body needs
// only 148 VGPRs standalone, so no spill expected (R5's failure was (256,4)
// which capped far below the accumulator's needs).
// Launch path now checks hipError_t of both the occupancy query and the
// cooperative launch; falls back to the proven split path only on failure.
// ws: fb bf16[B*D] | rp0/rp1[512*256] | cp0/cp1[64*33*256] | tmn[B] tmx[B]
// ---------------------------------------------------------------------------

typedef __attribute__((ext_vector_type(8))) short short8;   // 8 bf16
typedef __attribute__((ext_vector_type(4))) float floatx4;  // MFMA C/D

constexpr int D = 256;
constexpr int BM = 128;
constexpr int NT = 64;                    // 8192/128 strips
constexpr int NPB = 512;                  // pair blocks (64 strips x 8)
constexpr int CPS = 33;                   // cp slots per strip (off 0..32)

__device__ __forceinline__ unsigned f2bf(float f) {  // fp32 -> bf16, RNE
  unsigned u = __float_as_uint(f);
  return (u + 0x7FFFu + ((u >> 16) & 1u)) >> 16;
}

__device__ __forceinline__ void gl_lds16(const void* g, void* l) {
  __builtin_amdgcn_global_load_lds(
      (const __attribute__((address_space(1))) unsigned int*)g,
      (__attribute__((address_space(3))) unsigned int*)l, 16, 0, 0);
}

// ---------------- pair body (identical logic to R8, measured 61.8us) --------
template <int PASS>
__device__ __forceinline__ void pair_body(
    int bid, const unsigned short* __restrict__ fb, const int* __restrict__ labels,
    const float* __restrict__ tmn, const float* __restrict__ tmx,
    float* __restrict__ rp0, float* __restrict__ rp1,
    float* __restrict__ cp0, float* __restrict__ cp1,
    short* As, short* Bs, int* labA, float* tA0, float* tA1) {
  const int I   = bid >> 3;
  const int g   = bid & 7;
  const int nT  = (I < 32) ? 33 : 32;
  const int t0  = (g * nT) >> 3;
  const int t1  = ((g + 1) * nT) >> 3;
  const int row0 = I * BM;

  const int tid  = threadIdx.x;
  const int lane = tid & 63;
  const int wave = tid >> 6;
  const int l15  = lane & 15;
  const int quad = lane >> 4;
  const int wr   = (wave >> 1) * 64;
  const int wc   = (wave & 1) * 64;

  const float ONE_EPS = 1.0f - 1e-5f;
  const float INF = __builtin_inff();

  const int srow = (wave << 5) + (lane >> 3);
  const int slot = lane & 7;

  __syncthreads();                       // protect smem vs previous phase
  if (tid < BM) {
    labA[tid] = labels[row0 + tid];
    if (PASS == 2) { tA0[tid] = tmn[row0 + tid]; tA1[tid] = tmx[row0 + tid]; }
  }

  int arow[4], brow[4];
#pragma unroll
  for (int i = 0; i < 4; ++i) {
    arow[i] = wr + i * 16 + l15;
    brow[i] = wc + i * 16 + l15;
  }

  float s0[16], s1[16];
#pragma unroll
  for (int i = 0; i < 16; ++i) {
    s0[i] = (PASS == 1) ? INF : 0.f;
    s1[i] = (PASS == 1) ? -INF : 0.f;
  }

  for (int off = t0; off < t1; ++off) {
    const int J = (I + off) & 63;
    const int col0 = J * BM;
    const bool diag = (off == 0);

    floatx4 acc[4][4];
#pragma unroll
    for (int rf = 0; rf < 4; ++rf)
#pragma unroll
      for (int cf = 0; cf < 4; ++cf)
        acc[rf][cf] = (floatx4)(0.f);

    for (int kc = 0; kc < 4; ++kc) {
#pragma unroll
      for (int j = 0; j < 4; ++j) {
        int r = srow + 8 * j;
        int sw = (slot ^ (r & 7)) << 4;  // XOR swizzle (0 conflicts, measured)
        const char* ga = (const char*)fb + (((size_t)(row0 + r)) << 9) + (kc << 7) + sw;
        const char* gb = (const char*)fb + (((size_t)(col0 + r)) << 9) + (kc << 7) + sw;
        gl_lds16(ga, (char*)As + (r << 7) + (slot << 4));
        gl_lds16(gb, (char*)Bs + (r << 7) + (slot << 4));
      }
      __syncthreads();
#pragma unroll
      for (int ks = 0; ks < 2; ++ks) {
        const int gg = ks * 4 + quad;
        short8 a[4], b[4];
#pragma unroll
        for (int rf = 0; rf < 4; ++rf)
          a[rf] = *(const short8*)(As + arow[rf] * 64 + ((gg ^ (arow[rf] & 7)) << 3));
#pragma unroll
        for (int cf = 0; cf < 4; ++cf)
          b[cf] = *(const short8*)(Bs + brow[cf] * 64 + ((gg ^ (brow[cf] & 7)) << 3));
#pragma unroll
        for (int rf = 0; rf < 4; ++rf)
#pragma unroll
          for (int cf = 0; cf < 4; ++cf)
            acc[rf][cf] = __builtin_amdgcn_mfma_f32_16x16x32_bf16(a[rf], b[cf], acc[rf][cf], 0, 0, 0);
      }
      __syncthreads();
    }

    int labc[4];
    float tBn[4], tBx[4];
#pragma unroll
    for (int cf = 0; cf < 4; ++cf) {
      int ci = col0 + wc + cf * 16 + l15;
      labc[cf] = labels[ci];
      if (PASS == 2) { tBn[cf] = tmn[ci]; tBx[cf] = tmx[ci]; }
    }

    float c0[4], c1[4];
#pragma unroll
    for (int i = 0; i < 4; ++i) {
      c0[i] = (PASS == 1) ? INF : 0.f;
      c1[i] = (PASS == 1) ? -INF : 0.f;
    }

#pragma unroll
    for (int rf = 0; rf < 4; ++rf) {
#pragma unroll
      for (int r = 0; r < 4; ++r) {
        const int ri = wr + rf * 16 + quad * 4 + r;
        const int lr = labA[ri];
        float tRn = 0.f, tRx = 0.f;
        if (PASS == 2) { tRn = tA0[ri]; tRx = tA1[ri]; }
#pragma unroll
        for (int cf = 0; cf < 4; ++cf) {
          float sim = acc[rf][cf][r];
          bool same = (lr == labc[cf]);
          bool posok = same && (sim < ONE_EPS);
          if (PASS == 1) {
            float pc = posok ? sim : INF;
            float nc = same ? -INF : sim;
            s0[rf * 4 + r] = fminf(s0[rf * 4 + r], pc);
            s1[rf * 4 + r] = fmaxf(s1[rf * 4 + r], nc);
            c0[cf] = fminf(c0[cf], pc);
            c1[cf] = fmaxf(c1[cf], nc);
          } else {
            if (posok) {
              float e = __expf(fmaf(-2.f, sim, 1.f));
              if (sim < tRx)      s0[rf * 4 + r] += e;
              if (sim < tBx[cf])  c0[cf] += e;
            } else if (!same) {
              float e = (sim > 0.22f) ? __expf(fmaf(50.f, sim, -25.f)) : 0.f;
              if (sim > tRn)      s1[rf * 4 + r] += 1e-30f + e;
              if (sim > tBn[cf])  c1[cf] += 1e-30f + e;
            }
          }
        }
      }
    }

    if (!diag) {
#pragma unroll
      for (int cf = 0; cf < 4; ++cf) {
        float v = c0[cf], w = c1[cf];
#pragma unroll
        for (int m = 16; m < 64; m <<= 1) {
          float vv = __shfl_xor(v, m), ww = __shfl_xor(w, m);
          v = (PASS == 1) ? fminf(v, vv) : (v + vv);
          w = (PASS == 1) ? fmaxf(w, ww) : (w + ww);
        }
        if (quad == 0) {
          size_t o = (size_t)(I * CPS + off) * 256 + (size_t)(wr >> 6) * 128 + wc + cf * 16 + l15;
          cp0[o] = v;
          cp1[o] = w;
        }
      }
    }
  }

#pragma unroll
  for (int i = 0; i < 16; ++i) {
#pragma unroll
    for (int m = 1; m < 16; m <<= 1) {
      float v = __shfl_xor(s0[i], m), w = __shfl_xor(s1[i], m);
      s0[i] = (PASS == 1) ? fminf(s0[i], v) : (s0[i] + v);
      s1[i] = (PASS == 1) ? fmaxf(s1[i], w) : (s1[i] + w);
    }
  }
  if (l15 == 0) {
#pragma unroll
    for (int rf = 0; rf < 4; ++rf)
#pragma unroll
      for (int r = 0; r < 4; ++r) {
        int ri = wr + rf * 16 + quad * 4 + r;
        size_t o = (size_t)bid * 256 + (size_t)(wc >> 6) * 128 + ri;
        rp0[o] = s0[rf * 4 + r];
        rp1[o] = s1[rf * 4 + r];
      }
  }
}

// ---------------- reduce body (R8 logic) -----------------------------------
template <int PASS>
__device__ __forceinline__ void reduce_body(
    int T, const float* __restrict__ rp0, const float* __restrict__ rp1,
    const float* __restrict__ cp0, const float* __restrict__ cp1,
    float* __restrict__ o0, float* __restrict__ o1, float* __restrict__ out,
    float* sA, float* sB, float* sred) {
  const int q = threadIdx.x & 127;
  const int h = threadIdx.x >> 7;

  float a = (PASS == 1) ? __builtin_inff() : 0.f;
  float b = (PASS == 1) ? -__builtin_inff() : 0.f;
#pragma unroll
  for (int g = 0; g < 8; ++g) {
    size_t o = (size_t)(T * 8 + g) * 256 + (size_t)h * 128 + q;
    float v0 = rp0[o], v1 = rp1[o];
    a = (PASS == 1) ? fminf(a, v0) : (a + v0);
    b = (PASS == 1) ? fmaxf(b, v1) : (b + v1);
  }
  for (int I = 0; I < NT; ++I) {
    int off = (T - I) & 63;
    int lim = (I < 32) ? 32 : 31;
    if (off >= 1 && off <= lim) {
      size_t o = (size_t)(I * CPS + off) * 256 + (size_t)h * 128 + q;
      float v0 = cp0[o], v1 = cp1[o];
      a = (PASS == 1) ? fminf(a, v0) : (a + v0);
      b = (PASS == 1) ? fmaxf(b, v1) : (b + v1);
    }
  }
  if (h == 1) { sA[q] = a; sB[q] = b; }
  __syncthreads();
  if (h == 0) {
    a = (PASS == 1) ? fminf(a, sA[q]) : (a + sA[q]);
    b = (PASS == 1) ? fmaxf(b, sB[q]) : (b + sB[q]);
    if (PASS == 1) {
      o0[T * 128 + q] = a - 0.1f;
      o1[T * 128 + q] = b + 0.1f;
    } else {
      float loss = 0.f, cnt = 0.f;
      if (a > 0.f && b > 0.f) {
        loss = 0.5f * log1pf(a) + 0.02f * log1pf(b);
        cnt = 1.f;
      }
#pragma unroll
      for (int m = 1; m < 64; m <<= 1) {
        loss += __shfl_xor(loss, m);
        cnt  += __shfl_xor(cnt, m);
      }
      int wv = threadIdx.x >> 6, ln = threadIdx.x & 63;
      if (ln == 0) { sred[wv] = loss; sred[4 + wv] = cnt; }
    }
  }
  if (PASS == 2) {
    __syncthreads();
    if (threadIdx.x == 0) {
      float L = sred[0] + sred[1];
      float C = sred[4] + sred[5];
      atomicAdd(out, L / 8192.0f);
      atomicAdd(out + 1, -C / 8192.0f);
    }
  }
}

// ---------------- fused cooperative kernel ---------------------------------
// (256, 2): 2 waves/SIMD min -> VGPR capped at 256 -> 2 blocks/CU by VGPR,
// 4 by LDS -> maxb>=2 -> 512 coop blocks fit. pair_body needs 148 standalone,
// so no spill expected at the 256 cap.
__global__ __launch_bounds__(256, 2)
void mega_kernel(const float* feats, const int* labels, unsigned short* fb,
                 float* rp0, float* rp1, float* cp0, float* cp1,
                 float* tmn, float* tmx, float* out) {
  __shared__ __align__(16) short As[BM * 64];
  __shared__ __align__(16) short Bs[BM * 64];
  __shared__ int   labA[BM];
  __shared__ float tA0[BM], tA1[BM];

  cg::grid_group grid = cg::this_grid();
  const int bid = blockIdx.x;
  const int tid = threadIdx.x;

  // phase 0: convert fp32 -> bf16 (+ init out)
  const int n4 = 8192 * D / 4;
  for (int i = bid * 256 + tid; i < n4; i += NPB * 256) {
    float4 v = ((const float4*)feats)[i];
    unsigned lo = f2bf(v.x) | (f2bf(v.y) << 16);
    unsigned hi = f2bf(v.z) | (f2bf(v.w) << 16);
    ((uint2*)fb)[i] = make_uint2(lo, hi);
  }
  if (bid == 0 && tid == 0) { out[0] = 0.f; out[1] = 1.f; }
  __threadfence();
  grid.sync();

  // phase 1: pass1
  pair_body<1>(bid, fb, labels, nullptr, nullptr, rp0, rp1, cp0, cp1,
               As, Bs, labA, tA0, tA1);
  __threadfence();
  grid.sync();

  // phase 2: reduce1 -> thresholds
  if (bid < NT)
    reduce_body<1>(bid, rp0, rp1, cp0, cp1, tmn, tmx, out,
                   (float*)As, (float*)As + 128, (float*)As + 256);
  __threadfence();
  grid.sync();

  // phase 3: pass2
  pair_body<2>(bid, fb, labels, tmn, tmx, rp0, rp1, cp0, cp1,
               As, Bs, labA, tA0, tA1);
  __threadfence();
  grid.sync();

  // phase 4: reduce2 + finalize (atomics onto out)
  if (bid < NT)
    reduce_body<2>(bid, rp0, rp1, cp0, cp1, nullptr, nullptr, out,
                   (float*)As, (float*)As + 128, (float*)As + 256);
}

// ---------------- fallback split kernels (R8, proven 199.6us) --------------
__global__ void convert_kernel(const float* __restrict__ feats,
                               unsigned short* __restrict__ fb, int n4,
                               float* __restrict__ out) {
  int i = blockIdx.x * blockDim.x + threadIdx.x;
  if (i < n4) {
    float4 v = ((const float4*)feats)[i];
    unsigned lo = f2bf(v.x) | (f2bf(v.y) << 16);
    unsigned hi = f2bf(v.z) | (f2bf(v.w) << 16);
    ((uint2*)fb)[i] = make_uint2(lo, hi);
  }
  if (blockIdx.x == 0 && threadIdx.x == 0) { out[0] = 0.f; out[1] = 1.f; }
}

template <int PASS>
__global__ __launch_bounds__(256)
void pair_kernel(const unsigned short* __restrict__ fb, const int* __restrict__ labels,
                 const float* __restrict__ tmn, const float* __restrict__ tmx,
                 float* __restrict__ rp0, float* __restrict__ rp1,
                 float* __restrict__ cp0, float* __restrict__ cp1) {
  __shared__ __align__(16) short As[BM * 64];
  __shared__ __align__(16) short Bs[BM * 64];
  __shared__ int   labA[BM];
  __shared__ float tA0[BM], tA1[BM];
  pair_body<PASS>(blockIdx.x, fb, labels, tmn, tmx, rp0, rp1, cp0, cp1,
                  As, Bs, labA, tA0, tA1);
}

template <int PASS>
__global__ void reduce_kernel(const float* __restrict__ rp0, const float* __restrict__ rp1,
                              const float* __restrict__ cp0, const float* __restrict__ cp1,
                              float* __restrict__ o0, float* __restrict__ o1,
                              float* __restrict__ out) {
  __shared__ float sA[128], sB[128], sred[8];
  reduce_body<PASS>(blockIdx.x, rp0, rp1, cp0, cp1, o0, o1, out, sA, sB, sred);
}

extern "C" void kernel_launch(void* const* d_in, const int* in_sizes, int n_in,
                              void* d_out, int out_size, void* d_ws, size_t ws_size,
                              hipStream_t stream) {
  const float* feats  = (const float*)d_in[0];
  const int*   labels = (const int*)d_in[1];
  const int Bn = in_sizes[1];          // 8192
  float* out = (float*)d_out;

  unsigned short* fb = (unsigned short*)d_ws;                       // 4 MB
  float* rp0 = (float*)((char*)d_ws + (size_t)Bn * D * 2);
  float* rp1 = rp0 + (size_t)NPB * 256;
  float* cp0 = rp1 + (size_t)NPB * 256;
  float* cp1 = cp0 + (size_t)NT * CPS * 256;
  float* tmn = cp1 + (size_t)NT * CPS * 256;
  float* tmx = tmn + Bn;

  bool launched = false;
  int maxb = 0;
  hipError_t qe = hipOccupancyMaxActiveBlocksPerMultiprocessor(
      &maxb, (const void*)mega_kernel, 256, 0);
  if (qe == hipSuccess && maxb * 256 >= NPB) {
    void* args[] = {(void*)&feats, (void*)&labels, (void*)&fb,
                    (void*)&rp0, (void*)&rp1, (void*)&cp0, (void*)&cp1,
                    (void*)&tmn, (void*)&tmx, (void*)&out};
    hipError_t le = hipLaunchCooperativeKernel(
        (const void*)mega_kernel, dim3(NPB), dim3(256), args, 0, stream);
    launched = (le == hipSuccess);
  }
  if (!launched) {
    int n4 = Bn * D / 4;
    convert_kernel<<<(n4 + 255) / 256, 256, 0, stream>>>(feats, fb, n4, out);
    pair_kernel<1><<<NPB, 256, 0, stream>>>(fb, labels, nullptr, nullptr, rp0, rp1, cp0, cp1);
    reduce_kernel<1><<<NT, 256, 0, stream>>>(rp0, rp1, cp0, cp1, tmn, tmx, out);
    pair_kernel<2><<<NPB, 256, 0, stream>>>(fb, labels, tmn, tmx, rp0, rp1, cp0, cp1);
    reduce_kernel<2><<<NT, 256, 0, stream>>>(rp0, rp1, cp0, cp1, nullptr, nullptr, out);
  }
}

// Round 2
// 177.849 us; speedup vs baseline: 1.1170x; 1.1170x over previous
//
#include <hip/hip_runtime.h>
#include <hip/hip_cooperative_groups.h>
#include <stdint.h>

namespace cg = cooperative_groups;

// ---------------------------------------------------------------------------
// Speaker pairwise loss. R11 = R10's fused cooperative kernel (which launched,
// VGPR 124, but was neutral at 198.7us) + two targeted fixes:
//  (1) pair_body: double-buffered LDS staging with counted s_waitcnt vmcnt(8)
//      (raw s_barrier, never vmcnt(0) in steady state). R10's structure was
//      stage -> __syncthreads (FULL vmcnt drain) -> compute -> __syncthreads,
//      8 drain-barriers per off-tile; MFMA roofline is 6.9us/pass vs 60.8us
//      measured => stall-bound. Prefetch next kc-chunk before computing the
//      current one; loads stay in flight across the barrier (T3/T4 minimum).
//      LDS 34->66KB, still 2 blocks/CU (132 < 160KB).
//  (2) reduce_body: cp gather reindexed by off (I=(T-off)&63). off=1..31 are
//      unconditionally valid, off=32 valid iff T>=32 -> branch-free unrolled
//      loop, ~62 loads in flight instead of a 64-iter branchy serial chain.
// Everything else (tiling, swizzle, epilogue math, fencing) is byte-identical.
// ws: fb bf16[B*D] | rp0/rp1[512*256] | cp0/cp1[64*33*256] | tmn[B] tmx[B]
// ---------------------------------------------------------------------------

typedef __attribute__((ext_vector_type(8))) short short8;   // 8 bf16
typedef __attribute__((ext_vector_type(4))) float floatx4;  // MFMA C/D

constexpr int D = 256;
constexpr int BM = 128;
constexpr int NT = 64;                    // 8192/128 strips
constexpr int NPB = 512;                  // pair blocks (64 strips x 8)
constexpr int CPS = 33;                   // cp slots per strip (off 0..32)
constexpr int BUFS = BM * 64;             // shorts per LDS buffer (16KB)

__device__ __forceinline__ unsigned f2bf(float f) {  // fp32 -> bf16, RNE
  unsigned u = __float_as_uint(f);
  return (u + 0x7FFFu + ((u >> 16) & 1u)) >> 16;
}

__device__ __forceinline__ void gl_lds16(const void* g, void* l) {
  __builtin_amdgcn_global_load_lds(
      (const __attribute__((address_space(1))) unsigned int*)g,
      (__attribute__((address_space(3))) unsigned int*)l, 16, 0, 0);
}

// ---------------- pair body (dbuf + counted vmcnt) --------------------------
template <int PASS>
__device__ __forceinline__ void pair_body(
    int bid, const unsigned short* __restrict__ fb, const int* __restrict__ labels,
    const float* __restrict__ tmn, const float* __restrict__ tmx,
    float* __restrict__ rp0, float* __restrict__ rp1,
    float* __restrict__ cp0, float* __restrict__ cp1,
    short* As, short* Bs, int* labA, float* tA0, float* tA1) {
  const int I   = bid >> 3;
  const int g   = bid & 7;
  const int nT  = (I < 32) ? 33 : 32;
  const int t0  = (g * nT) >> 3;
  const int t1  = ((g + 1) * nT) >> 3;
  const int row0 = I * BM;

  const int tid  = threadIdx.x;
  const int lane = tid & 63;
  const int wave = tid >> 6;
  const int l15  = lane & 15;
  const int quad = lane >> 4;
  const int wr   = (wave >> 1) * 64;
  const int wc   = (wave & 1) * 64;

  const float ONE_EPS = 1.0f - 1e-5f;
  const float INF = __builtin_inff();

  const int srow = (wave << 5) + (lane >> 3);
  const int slot = lane & 7;

  __syncthreads();                       // protect smem vs previous phase
  if (tid < BM) {
    labA[tid] = labels[row0 + tid];
    if (PASS == 2) { tA0[tid] = tmn[row0 + tid]; tA1[tid] = tmx[row0 + tid]; }
  }

  // stage one 64-col chunk (kc) of the A-strip and of column-strip col0 into
  // LDS buffer b. 8 gl_lds16 per thread; XOR-swizzled global source, linear
  // LDS dest (m173 pattern). Each call = 8 outstanding vmcnt entries.
  auto stage = [&](int b, int col0, int kc) {
#pragma unroll
    for (int j = 0; j < 4; ++j) {
      int r = srow + 8 * j;
      int sw = (slot ^ (r & 7)) << 4;
      const char* ga = (const char*)fb + (((size_t)(row0 + r)) << 9) + (kc << 7) + sw;
      const char* gb = (const char*)fb + (((size_t)(col0 + r)) << 9) + (kc << 7) + sw;
      gl_lds16(ga, (char*)As + (size_t)b * (BUFS * 2) + (r << 7) + (slot << 4));
      gl_lds16(gb, (char*)Bs + (size_t)b * (BUFS * 2) + (r << 7) + (slot << 4));
    }
  };

  int arow[4], brow[4];
#pragma unroll
  for (int i = 0; i < 4; ++i) {
    arow[i] = wr + i * 16 + l15;
    brow[i] = wc + i * 16 + l15;
  }

  float s0[16], s1[16];
#pragma unroll
  for (int i = 0; i < 16; ++i) {
    s0[i] = (PASS == 1) ? INF : 0.f;
    s1[i] = (PASS == 1) ? -INF : 0.f;
  }

  // prologue: first off, first kc into buffer 0
  stage(0, ((I + t0) & 63) * BM, 0);

  int cur = 0;
  for (int off = t0; off < t1; ++off) {
    const int J = (I + off) & 63;
    const int col0 = J * BM;
    const bool diag = (off == 0);

    floatx4 acc[4][4];
#pragma unroll
    for (int rf = 0; rf < 4; ++rf)
#pragma unroll
      for (int cf = 0; cf < 4; ++cf)
        acc[rf][cf] = (floatx4)(0.f);

#pragma unroll
    for (int kc = 0; kc < 4; ++kc) {
      // prefetch next chunk into the alternate buffer, then wait ONLY for the
      // previous chunk (counted vmcnt — the 8 just-issued loads may remain).
      if (kc < 3) {
        stage(cur ^ 1, col0, kc + 1);
        asm volatile("s_waitcnt vmcnt(8)" ::: "memory");
      } else if (off + 1 < t1) {
        stage(cur ^ 1, ((I + off + 1) & 63) * BM, 0);
        asm volatile("s_waitcnt vmcnt(8)" ::: "memory");
      } else {
        asm volatile("s_waitcnt vmcnt(0)" ::: "memory");
      }
      __builtin_amdgcn_s_barrier();          // data-ready barrier
      asm volatile("" ::: "memory");

      const short* Ab = As + cur * BUFS;
      const short* Bb = Bs + cur * BUFS;
#pragma unroll
      for (int ks = 0; ks < 2; ++ks) {
        const int gg = ks * 4 + quad;
        short8 a[4], b[4];
#pragma unroll
        for (int rf = 0; rf < 4; ++rf)
          a[rf] = *(const short8*)(Ab + arow[rf] * 64 + ((gg ^ (arow[rf] & 7)) << 3));
#pragma unroll
        for (int cf = 0; cf < 4; ++cf)
          b[cf] = *(const short8*)(Bb + brow[cf] * 64 + ((gg ^ (brow[cf] & 7)) << 3));
#pragma unroll
        for (int rf = 0; rf < 4; ++rf)
#pragma unroll
          for (int cf = 0; cf < 4; ++cf)
            acc[rf][cf] = __builtin_amdgcn_mfma_f32_16x16x32_bf16(a[rf], b[cf], acc[rf][cf], 0, 0, 0);
      }
      asm volatile("s_waitcnt lgkmcnt(0)" ::: "memory");
      __builtin_amdgcn_s_barrier();          // buffer-free barrier
      asm volatile("" ::: "memory");
      cur ^= 1;
    }

    int labc[4];
    float tBn[4], tBx[4];
#pragma unroll
    for (int cf = 0; cf < 4; ++cf) {
      int ci = col0 + wc + cf * 16 + l15;
      labc[cf] = labels[ci];
      if (PASS == 2) { tBn[cf] = tmn[ci]; tBx[cf] = tmx[ci]; }
    }

    float c0[4], c1[4];
#pragma unroll
    for (int i = 0; i < 4; ++i) {
      c0[i] = (PASS == 1) ? INF : 0.f;
      c1[i] = (PASS == 1) ? -INF : 0.f;
    }

#pragma unroll
    for (int rf = 0; rf < 4; ++rf) {
#pragma unroll
      for (int r = 0; r < 4; ++r) {
        const int ri = wr + rf * 16 + quad * 4 + r;
        const int lr = labA[ri];
        float tRn = 0.f, tRx = 0.f;
        if (PASS == 2) { tRn = tA0[ri]; tRx = tA1[ri]; }
#pragma unroll
        for (int cf = 0; cf < 4; ++cf) {
          float sim = acc[rf][cf][r];
          bool same = (lr == labc[cf]);
          bool posok = same && (sim < ONE_EPS);
          if (PASS == 1) {
            float pc = posok ? sim : INF;
            float nc = same ? -INF : sim;
            s0[rf * 4 + r] = fminf(s0[rf * 4 + r], pc);
            s1[rf * 4 + r] = fmaxf(s1[rf * 4 + r], nc);
            c0[cf] = fminf(c0[cf], pc);
            c1[cf] = fmaxf(c1[cf], nc);
          } else {
            if (posok) {
              float e = __expf(fmaf(-2.f, sim, 1.f));
              if (sim < tRx)      s0[rf * 4 + r] += e;
              if (sim < tBx[cf])  c0[cf] += e;
            } else if (!same) {
              float e = (sim > 0.22f) ? __expf(fmaf(50.f, sim, -25.f)) : 0.f;
              if (sim > tRn)      s1[rf * 4 + r] += 1e-30f + e;
              if (sim > tBn[cf])  c1[cf] += 1e-30f + e;
            }
          }
        }
      }
    }

    if (!diag) {
#pragma unroll
      for (int cf = 0; cf < 4; ++cf) {
        float v = c0[cf], w = c1[cf];
#pragma unroll
        for (int m = 16; m < 64; m <<= 1) {
          float vv = __shfl_xor(v, m), ww = __shfl_xor(w, m);
          v = (PASS == 1) ? fminf(v, vv) : (v + vv);
          w = (PASS == 1) ? fmaxf(w, ww) : (w + ww);
        }
        if (quad == 0) {
          size_t o = (size_t)(I * CPS + off) * 256 + (size_t)(wr >> 6) * 128 + wc + cf * 16 + l15;
          cp0[o] = v;
          cp1[o] = w;
        }
      }
    }
  }

#pragma unroll
  for (int i = 0; i < 16; ++i) {
#pragma unroll
    for (int m = 1; m < 16; m <<= 1) {
      float v = __shfl_xor(s0[i], m), w = __shfl_xor(s1[i], m);
      s0[i] = (PASS == 1) ? fminf(s0[i], v) : (s0[i] + v);
      s1[i] = (PASS == 1) ? fmaxf(s1[i], w) : (s1[i] + w);
    }
  }
  if (l15 == 0) {
#pragma unroll
    for (int rf = 0; rf < 4; ++rf)
#pragma unroll
      for (int r = 0; r < 4; ++r) {
        int ri = wr + rf * 16 + quad * 4 + r;
        size_t o = (size_t)bid * 256 + (size_t)(wc >> 6) * 128 + ri;
        rp0[o] = s0[rf * 4 + r];
        rp1[o] = s1[rf * 4 + r];
      }
  }
}

// ---------------- reduce body (ILP-restructured cp gather) ------------------
template <int PASS>
__device__ __forceinline__ void reduce_body(
    int T, const float* __restrict__ rp0, const float* __restrict__ rp1,
    const float* __restrict__ cp0, const float* __restrict__ cp1,
    float* __restrict__ o0, float* __restrict__ o1, float* __restrict__ out,
    float* sA, float* sB, float* sred) {
  const int q = threadIdx.x & 127;
  const int h = threadIdx.x >> 7;

  float a = (PASS == 1) ? __builtin_inff() : 0.f;
  float b = (PASS == 1) ? -__builtin_inff() : 0.f;
#pragma unroll
  for (int g = 0; g < 8; ++g) {
    size_t o = (size_t)(T * 8 + g) * 256 + (size_t)h * 128 + q;
    float v0 = rp0[o], v1 = rp1[o];
    a = (PASS == 1) ? fminf(a, v0) : (a + v0);
    b = (PASS == 1) ? fmaxf(b, v1) : (b + v1);
  }
  // cp gather reindexed by off: I=(T-off)&63. For off=1..31 always valid
  // (lim >= 31); off=32 valid iff I<32 iff T>=32. Branch-free -> full unroll,
  // all loads issued back-to-back (was a 64-iter branchy serial chain).
#pragma unroll
  for (int off = 1; off <= 31; ++off) {
    int Is = (T - off) & 63;
    size_t o = (size_t)(Is * CPS + off) * 256 + (size_t)h * 128 + q;
    float v0 = cp0[o], v1 = cp1[o];
    a = (PASS == 1) ? fminf(a, v0) : (a + v0);
    b = (PASS == 1) ? fmaxf(b, v1) : (b + v1);
  }
  if (T >= 32) {
    int Is = T - 32;
    size_t o = (size_t)(Is * CPS + 32) * 256 + (size_t)h * 128 + q;
    float v0 = cp0[o], v1 = cp1[o];
    a = (PASS == 1) ? fminf(a, v0) : (a + v0);
    b = (PASS == 1) ? fmaxf(b, v1) : (b + v1);
  }
  if (h == 1) { sA[q] = a; sB[q] = b; }
  __syncthreads();
  if (h == 0) {
    a = (PASS == 1) ? fminf(a, sA[q]) : (a + sA[q]);
    b = (PASS == 1) ? fmaxf(b, sB[q]) : (b + sB[q]);
    if (PASS == 1) {
      o0[T * 128 + q] = a - 0.1f;
      o1[T * 128 + q] = b + 0.1f;
    } else {
      float loss = 0.f, cnt = 0.f;
      if (a > 0.f && b > 0.f) {
        loss = 0.5f * log1pf(a) + 0.02f * log1pf(b);
        cnt = 1.f;
      }
#pragma unroll
      for (int m = 1; m < 64; m <<= 1) {
        loss += __shfl_xor(loss, m);
        cnt  += __shfl_xor(cnt, m);
      }
      int wv = threadIdx.x >> 6, ln = threadIdx.x & 63;
      if (ln == 0) { sred[wv] = loss; sred[4 + wv] = cnt; }
    }
  }
  if (PASS == 2) {
    __syncthreads();
    if (threadIdx.x == 0) {
      float L = sred[0] + sred[1];
      float C = sred[4] + sred[5];
      atomicAdd(out, L / 8192.0f);
      atomicAdd(out + 1, -C / 8192.0f);
    }
  }
}

// ---------------- fused cooperative kernel ---------------------------------
// (256, 2): VGPR cap 256, 2 blocks/CU. LDS: 2x(As+Bs dbuf 32KB) = 64KB +
// labels/thresholds ~2KB -> ~66KB; 2 blocks/CU = 132KB <= 160KB. maxb >= 2.
__global__ __launch_bounds__(256, 2)
void mega_kernel(const float* feats, const int* labels, unsigned short* fb,
                 float* rp0, float* rp1, float* cp0, float* cp1,
                 float* tmn, float* tmx, float* out) {
  __shared__ __align__(16) short As[2 * BUFS];
  __shared__ __align__(16) short Bs[2 * BUFS];
  __shared__ int   labA[BM];
  __shared__ float tA0[BM], tA1[BM];

  cg::grid_group grid = cg::this_grid();
  const int bid = blockIdx.x;
  const int tid = threadIdx.x;

  // phase 0: convert fp32 -> bf16 (+ init out)
  const int n4 = 8192 * D / 4;
  for (int i = bid * 256 + tid; i < n4; i += NPB * 256) {
    float4 v = ((const float4*)feats)[i];
    unsigned lo = f2bf(v.x) | (f2bf(v.y) << 16);
    unsigned hi = f2bf(v.z) | (f2bf(v.w) << 16);
    ((uint2*)fb)[i] = make_uint2(lo, hi);
  }
  if (bid == 0 && tid == 0) { out[0] = 0.f; out[1] = 1.f; }
  __threadfence();
  grid.sync();

  // phase 1: pass1
  pair_body<1>(bid, fb, labels, nullptr, nullptr, rp0, rp1, cp0, cp1,
               As, Bs, labA, tA0, tA1);
  __threadfence();
  grid.sync();

  // phase 2: reduce1 -> thresholds
  if (bid < NT)
    reduce_body<1>(bid, rp0, rp1, cp0, cp1, tmn, tmx, out,
                   (float*)As, (float*)As + 128, (float*)As + 256);
  __threadfence();
  grid.sync();

  // phase 3: pass2
  pair_body<2>(bid, fb, labels, tmn, tmx, rp0, rp1, cp0, cp1,
               As, Bs, labA, tA0, tA1);
  __threadfence();
  grid.sync();

  // phase 4: reduce2 + finalize (atomics onto out)
  if (bid < NT)
    reduce_body<2>(bid, rp0, rp1, cp0, cp1, nullptr, nullptr, out,
                   (float*)As, (float*)As + 128, (float*)As + 256);
}

// ---------------- fallback split kernels -----------------------------------
__global__ void convert_kernel(const float* __restrict__ feats,
                               unsigned short* __restrict__ fb, int n4,
                               float* __restrict__ out) {
  int i = blockIdx.x * blockDim.x + threadIdx.x;
  if (i < n4) {
    float4 v = ((const float4*)feats)[i];
    unsigned lo = f2bf(v.x) | (f2bf(v.y) << 16);
    unsigned hi = f2bf(v.z) | (f2bf(v.w) << 16);
    ((uint2*)fb)[i] = make_uint2(lo, hi);
  }
  if (blockIdx.x == 0 && threadIdx.x == 0) { out[0] = 0.f; out[1] = 1.f; }
}

template <int PASS>
__global__ __launch_bounds__(256)
void pair_kernel(const unsigned short* __restrict__ fb, const int* __restrict__ labels,
                 const float* __restrict__ tmn, const float* __restrict__ tmx,
                 float* __restrict__ rp0, float* __restrict__ rp1,
                 float* __restrict__ cp0, float* __restrict__ cp1) {
  __shared__ __align__(16) short As[2 * BUFS];
  __shared__ __align__(16) short Bs[2 * BUFS];
  __shared__ int   labA[BM];
  __shared__ float tA0[BM], tA1[BM];
  pair_body<PASS>(blockIdx.x, fb, labels, tmn, tmx, rp0, rp1, cp0, cp1,
                  As, Bs, labA, tA0, tA1);
}

template <int PASS>
__global__ void reduce_kernel(const float* __restrict__ rp0, const float* __restrict__ rp1,
                              const float* __restrict__ cp0, const float* __restrict__ cp1,
                              float* __restrict__ o0, float* __restrict__ o1,
                              float* __restrict__ out) {
  __shared__ float sA[128], sB[128], sred[8];
  reduce_body<PASS>(blockIdx.x, rp0, rp1, cp0, cp1, o0, o1, out, sA, sB, sred);
}

extern "C" void kernel_launch(void* const* d_in, const int* in_sizes, int n_in,
                              void* d_out, int out_size, void* d_ws, size_t ws_size,
                              hipStream_t stream) {
  const float* feats  = (const float*)d_in[0];
  const int*   labels = (const int*)d_in[1];
  const int Bn = in_sizes[1];          // 8192
  float* out = (float*)d_out;

  unsigned short* fb = (unsigned short*)d_ws;                       // 4 MB
  float* rp0 = (float*)((char*)d_ws + (size_t)Bn * D * 2);
  float* rp1 = rp0 + (size_t)NPB * 256;
  float* cp0 = rp1 + (size_t)NPB * 256;
  float* cp1 = cp0 + (size_t)NT * CPS * 256;
  float* tmn = cp1 + (size_t)NT * CPS * 256;
  float* tmx = tmn + Bn;

  bool launched = false;
  int maxb = 0;
  hipError_t qe = hipOccupancyMaxActiveBlocksPerMultiprocessor(
      &maxb, (const void*)mega_kernel, 256, 0);
  if (qe == hipSuccess && maxb * 256 >= NPB) {
    void* args[] = {(void*)&feats, (void*)&labels, (void*)&fb,
                    (void*)&rp0, (void*)&rp1, (void*)&cp0, (void*)&cp1,
                    (void*)&tmn, (void*)&tmx, (void*)&out};
    hipError_t le = hipLaunchCooperativeKernel(
        (const void*)mega_kernel, dim3(NPB), dim3(256), args, 0, stream);
    launched = (le == hipSuccess);
  }
  if (!launched) {
    int n4 = Bn * D / 4;
    convert_kernel<<<(n4 + 255) / 256, 256, 0, stream>>>(feats, fb, n4, out);
    pair_kernel<1><<<NPB, 256, 0, stream>>>(fb, labels, nullptr, nullptr, rp0, rp1, cp0, cp1);
    reduce_kernel<1><<<NT, 256, 0, stream>>>(rp0, rp1, cp0, cp1, tmn, tmx, out);
    pair_kernel<2><<<NPB, 256, 0, stream>>>(fb, labels, tmn, tmx, rp0, rp1, cp0, cp1);
    reduce_kernel<2><<<NT, 256, 0, stream>>>(rp0, rp1, cp0, cp1, nullptr, nullptr, out);
  }
}